// Round 1
// baseline (357.100 us; speedup 1.0000x reference)
//
#include <hip/hip_runtime.h>
#include <hip/hip_bf16.h>

// out[b,s,o] = scale[o] * dot(x[b,s,:], w_eff[o,:])
//   w_eff = weight + 2.0*(b_w @ a_w);  scale[o] = magnitude[o]/||w_eff[o,:]||
// Phase 1: prep kernel builds w_eff (bf16, in ws) + scale (fp32, in ws).
// Phase 2: bf16-MFMA GEMM, M=32768 N=1024 K=1024, fp32 accum + fp32 epilogue scale.

typedef __bf16 bf16x8 __attribute__((ext_vector_type(8)));
typedef __bf16 bf16x4 __attribute__((ext_vector_type(4)));
typedef float  f32x4  __attribute__((ext_vector_type(4)));

#define D_IN  1024
#define D_OUT 1024
#define M_TOT 32768
#define BM 128
#define BN 128
#define BK 32
#define LDS_STRIDE 56   // bf16 elems; 112B = 28 words -> 2-way bank alias (free), 16B aligned rows

__global__ void dora_prep(const float* __restrict__ w,
                          const float* __restrict__ a_w,
                          const float* __restrict__ b_w,
                          const float* __restrict__ mag,
                          __bf16* __restrict__ wb,
                          float* __restrict__ scale) {
    const int o = blockIdx.x;      // output row
    const int t = threadIdx.x;     // 256 threads

    float bw[16];
#pragma unroll
    for (int r = 0; r < 16; ++r) bw[r] = b_w[o * 16 + r];

    float ss = 0.f;
#pragma unroll
    for (int i = 0; i < 4; ++i) {
        const int k = t + i * 256;
        float dot = 0.f;
#pragma unroll
        for (int r = 0; r < 16; ++r) dot = fmaf(bw[r], a_w[r * D_IN + k], dot);
        const float acc = fmaf(2.0f, dot, w[o * D_IN + k]);  // w_eff in fp32
        wb[o * D_IN + k] = (__bf16)acc;
        ss = fmaf(acc, acc, ss);
    }
    // wave reduce (64 lanes)
#pragma unroll
    for (int off = 32; off; off >>= 1) ss += __shfl_down(ss, off, 64);
    __shared__ float wsum[4];
    if ((t & 63) == 0) wsum[t >> 6] = ss;
    __syncthreads();
    if (t == 0) {
        const float tot = wsum[0] + wsum[1] + wsum[2] + wsum[3];
        scale[o] = mag[o] / sqrtf(tot);
    }
}

__global__ void dora_gemm(const float* __restrict__ x,
                          const __bf16* __restrict__ wb,
                          const float* __restrict__ scale,
                          float* __restrict__ out) {
    __shared__ __bf16 As[BM][LDS_STRIDE];
    __shared__ __bf16 Bs[BN][LDS_STRIDE];

    const int bx = blockIdx.x;
    const int bn = (bx & 7) * BN;       // N fastest -> 8 consecutive blocks share x tile (L2/LLC reuse)
    const int bm = (bx >> 3) * BM;
    const int t  = threadIdx.x;
    const int lane = t & 63;
    const int wave = t >> 6;
    const int wm = (wave & 1) * 64;
    const int wn = (wave >> 1) * 64;
    const int lm = lane & 15;           // m (A) / n (B) index within 16-tile
    const int lq = lane >> 4;           // quad -> k chunk of 8

    f32x4 acc[4][4] = {};

    const float* xbase = x + (size_t)bm * D_IN;
    const __bf16* wbase = wb + (size_t)bn * D_IN;

    for (int kk = 0; kk < D_IN; kk += BK) {
        // ---- stage A: fp32 -> bf16; 4 rounds; 8 lanes cover 128B contiguous per row
#pragma unroll
        for (int j = 0; j < 4; ++j) {
            const int r = j * 32 + (t >> 3);
            const int k = (t & 7) * 4;
            const float4 v = *(const float4*)(xbase + (size_t)r * D_IN + kk + k);
            bf16x4 p = { (__bf16)v.x, (__bf16)v.y, (__bf16)v.z, (__bf16)v.w };
            *(bf16x4*)(&As[r][k]) = p;   // ds_write_b64
        }
        // ---- stage B: bf16 direct; 2 rounds; 4 lanes cover 64B contiguous per row
#pragma unroll
        for (int j = 0; j < 2; ++j) {
            const int n = j * 64 + (t >> 2);
            const int k = (t & 3) * 8;
            bf16x8 v = *(const bf16x8*)(wbase + (size_t)n * D_IN + kk + k);
            *(bf16x8*)(&Bs[n][k]) = v;   // ds_write_b128
        }
        __syncthreads();

        bf16x8 af[4], bfr[4];
#pragma unroll
        for (int i = 0; i < 4; ++i)
            af[i] = *(const bf16x8*)(&As[wm + i * 16 + lm][lq * 8]);
#pragma unroll
        for (int i = 0; i < 4; ++i)
            bfr[i] = *(const bf16x8*)(&Bs[wn + i * 16 + lm][lq * 8]);

#pragma unroll
        for (int i = 0; i < 4; ++i)
#pragma unroll
            for (int j = 0; j < 4; ++j)
                acc[i][j] = __builtin_amdgcn_mfma_f32_16x16x32_bf16(af[i], bfr[j], acc[i][j], 0, 0, 0);
        __syncthreads();
    }

    // ---- epilogue: C/D map col = lane&15 (n), row = (lane>>4)*4 + reg (m)
#pragma unroll
    for (int j = 0; j < 4; ++j) {
        const int n = bn + wn + j * 16 + lm;
        const float sc = scale[n];
#pragma unroll
        for (int i = 0; i < 4; ++i) {
            const int m = bm + wm + i * 16 + lq * 4;
#pragma unroll
            for (int r = 0; r < 4; ++r) {
                out[(size_t)(m + r) * D_OUT + n] = acc[i][j][r] * sc;
            }
        }
    }
}

extern "C" void kernel_launch(void* const* d_in, const int* in_sizes, int n_in,
                              void* d_out, int out_size, void* d_ws, size_t ws_size,
                              hipStream_t stream) {
    const float* x    = (const float*)d_in[0];   // [4,8192,1024]
    const float* w    = (const float*)d_in[1];   // [1024,1024]
    const float* a_w  = (const float*)d_in[2];   // [16,1024]
    const float* b_w  = (const float*)d_in[3];   // [1024,16]
    const float* mag  = (const float*)d_in[4];   // [1,1024]
    float* out = (float*)d_out;                  // [4,8192,1024] fp32

    __bf16* wb   = (__bf16*)d_ws;                             // 2 MB: w_eff bf16
    float* scale = (float*)((char*)d_ws + (size_t)D_OUT * D_IN * sizeof(__bf16)); // 4 KB

    dora_prep<<<D_OUT, 256, 0, stream>>>(w, a_w, b_w, mag, wb, scale);

    const int grid = (M_TOT / BM) * (D_OUT / BN);  // 256 * 8 = 2048
    dora_gemm<<<grid, 256, 0, stream>>>(x, wb, scale, out);
}

// Round 2
// 333.680 us; speedup vs baseline: 1.0702x; 1.0702x over previous
//
#include <hip/hip_runtime.h>
#include <hip/hip_bf16.h>

// out[b,s,o] = scale[o] * dot(x[b,s,:], w_eff[o,:])
//   w_eff = weight + 2.0*(b_w @ a_w);  scale[o] = magnitude[o]/||w_eff[o,:]||
// Phase 0: x (fp32) -> bf16 into ws              (bandwidth-bound, ~35us)
// Phase 1: prep builds w_eff bf16 + scale fp32   (~10us)
// Phase 2: m97-style bf16 MFMA GEMM with global_load_lds width=16 staging.

typedef __bf16 bf16x8 __attribute__((ext_vector_type(8)));
typedef __bf16 bf16x4 __attribute__((ext_vector_type(4)));
typedef float  f32x4  __attribute__((ext_vector_type(4)));

#define D_IN  1024
#define D_OUT 1024
#define M_TOT 32768
#define BM 128
#define BN 128
#define BK 32

__device__ __forceinline__ void gl_lds16(const __bf16* g, __bf16* l) {
    // HBM -> LDS DMA, 16B per lane; LDS dest = wave-uniform base + lane*16.
    __builtin_amdgcn_global_load_lds(
        (const __attribute__((address_space(1))) void*)g,
        (__attribute__((address_space(3))) void*)l,
        16, 0, 0);
}

__global__ void x_to_bf16(const float* __restrict__ x, __bf16* __restrict__ xb) {
    const size_t idx = ((size_t)blockIdx.x * blockDim.x + threadIdx.x) * 8;
    const float4 v0 = *(const float4*)(x + idx);
    const float4 v1 = *(const float4*)(x + idx + 4);
    bf16x8 p = { (__bf16)v0.x, (__bf16)v0.y, (__bf16)v0.z, (__bf16)v0.w,
                 (__bf16)v1.x, (__bf16)v1.y, (__bf16)v1.z, (__bf16)v1.w };
    *(bf16x8*)(xb + idx) = p;
}

__global__ void dora_prep(const float* __restrict__ w,
                          const float* __restrict__ a_w,
                          const float* __restrict__ b_w,
                          const float* __restrict__ mag,
                          __bf16* __restrict__ wb,
                          float* __restrict__ scale) {
    const int o = blockIdx.x;
    const int t = threadIdx.x;

    float bw[16];
#pragma unroll
    for (int r = 0; r < 16; ++r) bw[r] = b_w[o * 16 + r];

    float ss = 0.f;
#pragma unroll
    for (int i = 0; i < 4; ++i) {
        const int k = t + i * 256;
        float dot = 0.f;
#pragma unroll
        for (int r = 0; r < 16; ++r) dot = fmaf(bw[r], a_w[r * D_IN + k], dot);
        const float acc = fmaf(2.0f, dot, w[o * D_IN + k]);
        wb[o * D_IN + k] = (__bf16)acc;
        ss = fmaf(acc, acc, ss);
    }
#pragma unroll
    for (int off = 32; off; off >>= 1) ss += __shfl_down(ss, off, 64);
    __shared__ float wsum[4];
    if ((t & 63) == 0) wsum[t >> 6] = ss;
    __syncthreads();
    if (t == 0) {
        const float tot = wsum[0] + wsum[1] + wsum[2] + wsum[3];
        scale[o] = mag[o] / sqrtf(tot);
    }
}

__global__ void dora_gemm(const __bf16* __restrict__ xb,
                          const __bf16* __restrict__ wb,
                          const float* __restrict__ scale,
                          float* __restrict__ out) {
    // Unpadded contiguous tiles (global_load_lds requires lane-contiguous dest).
    __shared__ __bf16 As[BM * BK];   // 8 KB, row-major [128][32]
    __shared__ __bf16 Bs[BN * BK];   // 8 KB

    const int bx = blockIdx.x;
    const int bn = (bx & 7) * BN;       // N fastest: 8 consecutive blocks share x rows
    const int bm = (bx >> 3) * BM;
    const int t  = threadIdx.x;
    const int lane = t & 63;
    const int wave = t >> 6;
    const int wm = (wave & 1) * 64;
    const int wn = (wave >> 1) * 64;
    const int lm = lane & 15;
    const int lq = lane >> 4;

    f32x4 acc[4][4] = {};

    // Staging map: per K-iter each tile is 8KB = 8 chunks of 1KB (16 rows x 64B).
    // Wave w stages chunks {2w, 2w+1} of A and of B. Lane i covers row i>>2,
    // byte col (i&3)*16 -> LDS byte offset 16*i (contiguous). 
    const int srow0 = wave * 32 + (lane >> 2);        // chunk j=0 row
    const int scol  = (lane & 3) * 8;                 // bf16 elems
    const __bf16* ag0 = xb + (size_t)(bm + srow0) * D_IN + scol;
    const __bf16* ag1 = ag0 + 16 * D_IN;              // chunk j=1
    const __bf16* bg0 = wb + (size_t)(bn + srow0) * D_IN + scol;
    const __bf16* bg1 = bg0 + 16 * D_IN;
    __bf16* al0 = As + wave * 1024;                   // wave-uniform LDS bases
    __bf16* al1 = As + wave * 1024 + 512;
    __bf16* bl0 = Bs + wave * 1024;
    __bf16* bl1 = Bs + wave * 1024 + 512;

    for (int kk = 0; kk < D_IN; kk += BK) {
        gl_lds16(ag0 + kk, al0);
        gl_lds16(ag1 + kk, al1);
        gl_lds16(bg0 + kk, bl0);
        gl_lds16(bg1 + kk, bl1);
        __syncthreads();   // compiler emits s_waitcnt vmcnt(0) before s_barrier

        bf16x8 af[4], bfr[4];
#pragma unroll
        for (int i = 0; i < 4; ++i)
            af[i] = *(const bf16x8*)(&As[(wm + i * 16 + lm) * BK + lq * 8]);
#pragma unroll
        for (int i = 0; i < 4; ++i)
            bfr[i] = *(const bf16x8*)(&Bs[(wn + i * 16 + lm) * BK + lq * 8]);

#pragma unroll
        for (int i = 0; i < 4; ++i)
#pragma unroll
            for (int j = 0; j < 4; ++j)
                acc[i][j] = __builtin_amdgcn_mfma_f32_16x16x32_bf16(af[i], bfr[j], acc[i][j], 0, 0, 0);
        __syncthreads();
    }

    // C/D map: col = lane&15 (n), row = (lane>>4)*4 + reg (m)
#pragma unroll
    for (int j = 0; j < 4; ++j) {
        const int n = bn + wn + j * 16 + lm;
        const float sc = scale[n];
#pragma unroll
        for (int i = 0; i < 4; ++i) {
            const int m = bm + wm + i * 16 + lq * 4;
#pragma unroll
            for (int r = 0; r < 4; ++r) {
                out[(size_t)(m + r) * D_OUT + n] = acc[i][j][r] * sc;
            }
        }
    }
}

extern "C" void kernel_launch(void* const* d_in, const int* in_sizes, int n_in,
                              void* d_out, int out_size, void* d_ws, size_t ws_size,
                              hipStream_t stream) {
    const float* x    = (const float*)d_in[0];   // [4,8192,1024] fp32
    const float* w    = (const float*)d_in[1];   // [1024,1024]
    const float* a_w  = (const float*)d_in[2];   // [16,1024]
    const float* b_w  = (const float*)d_in[3];   // [1024,16]
    const float* mag  = (const float*)d_in[4];   // [1,1024]
    float* out = (float*)d_out;                  // [4,8192,1024] fp32

    __bf16* xb   = (__bf16*)d_ws;                                  // 64 MB
    __bf16* wb   = (__bf16*)((char*)d_ws + (size_t)M_TOT * D_IN * 2);  // 2 MB
    float* scale = (float*)((char*)wb + (size_t)D_OUT * D_IN * 2); // 4 KB

    x_to_bf16<<<(M_TOT * D_IN) / (256 * 8), 256, 0, stream>>>(x, xb);
    dora_prep<<<D_OUT, 256, 0, stream>>>(w, a_w, b_w, mag, wb, scale);

    const int grid = (M_TOT / BM) * (D_OUT / BN);  // 2048
    dora_gemm<<<grid, 256, 0, stream>>>(xb, wb, scale, out);
}

// Round 3
// 318.942 us; speedup vs baseline: 1.1196x; 1.0462x over previous
//
#include <hip/hip_runtime.h>
#include <hip/hip_bf16.h>

// out[b,s,o] = scale[o] * dot(x[b,s,:], w_eff[o,:])
//   w_eff = weight + 2.0*(b_w @ a_w);  scale[o] = magnitude[o]/||w_eff[o,:]||
// Phase 0: x (fp32) -> bf16 into ws              (bandwidth-bound, ~30us)
// Phase 1: prep builds w_eff bf16 + scale fp32   (~10us)
// Phase 2: m97-style bf16 MFMA GEMM, global_load_lds width=16 staging,
//          XCD-aware block swizzle (blocks sharing an A tile -> same XCD L2).

typedef __bf16 bf16x8 __attribute__((ext_vector_type(8)));
typedef __bf16 bf16x4 __attribute__((ext_vector_type(4)));
typedef float  f32x4  __attribute__((ext_vector_type(4)));

#define D_IN  1024
#define D_OUT 1024
#define M_TOT 32768
#define BM 128
#define BN 128
#define BK 32

__device__ __forceinline__ void gl_lds16(const __bf16* g, __bf16* l) {
    // HBM -> LDS DMA, 16B per lane; LDS dest = wave-uniform base + lane*16.
    __builtin_amdgcn_global_load_lds(
        (const __attribute__((address_space(1))) void*)g,
        (__attribute__((address_space(3))) void*)l,
        16, 0, 0);
}

__global__ void x_to_bf16(const float* __restrict__ x, __bf16* __restrict__ xb) {
    const size_t idx = ((size_t)blockIdx.x * blockDim.x + threadIdx.x) * 8;
    const float4 v0 = *(const float4*)(x + idx);
    const float4 v1 = *(const float4*)(x + idx + 4);
    bf16x8 p = { (__bf16)v0.x, (__bf16)v0.y, (__bf16)v0.z, (__bf16)v0.w,
                 (__bf16)v1.x, (__bf16)v1.y, (__bf16)v1.z, (__bf16)v1.w };
    *(bf16x8*)(xb + idx) = p;
}

__global__ void dora_prep(const float* __restrict__ w,
                          const float* __restrict__ a_w,
                          const float* __restrict__ b_w,
                          const float* __restrict__ mag,
                          __bf16* __restrict__ wb,
                          float* __restrict__ scale) {
    const int o = blockIdx.x;
    const int t = threadIdx.x;

    float bw[16];
#pragma unroll
    for (int r = 0; r < 16; ++r) bw[r] = b_w[o * 16 + r];

    float ss = 0.f;
#pragma unroll
    for (int i = 0; i < 4; ++i) {
        const int k = t + i * 256;
        float dot = 0.f;
#pragma unroll
        for (int r = 0; r < 16; ++r) dot = fmaf(bw[r], a_w[r * D_IN + k], dot);
        const float acc = fmaf(2.0f, dot, w[o * D_IN + k]);
        wb[o * D_IN + k] = (__bf16)acc;
        ss = fmaf(acc, acc, ss);
    }
#pragma unroll
    for (int off = 32; off; off >>= 1) ss += __shfl_down(ss, off, 64);
    __shared__ float wsum[4];
    if ((t & 63) == 0) wsum[t >> 6] = ss;
    __syncthreads();
    if (t == 0) {
        const float tot = wsum[0] + wsum[1] + wsum[2] + wsum[3];
        scale[o] = mag[o] / sqrtf(tot);
    }
}

__global__ void dora_gemm(const __bf16* __restrict__ xb,
                          const __bf16* __restrict__ wb,
                          const float* __restrict__ scale,
                          float* __restrict__ out) {
    // Unpadded contiguous tiles (global_load_lds requires lane-contiguous dest).
    __shared__ __bf16 As[BM * BK];   // 8 KB, row-major [128][32]
    __shared__ __bf16 Bs[BN * BK];   // 8 KB

    const int bx = blockIdx.x;
    // XCD-aware swizzle: consecutive blockIdx round-robin across 8 XCDs
    // (xcd = bx & 7). Give each XCD 32 contiguous bm tiles, bn fastest, so the
    // 8 blocks sharing an A tile sit on ONE XCD's L2 at the same time.
    const int xcd = bx & 7;
    const int l   = bx >> 3;                  // 0..255 local index on this XCD
    const int bm  = (xcd * 32 + (l >> 3)) * BM;
    const int bn  = (l & 7) * BN;

    const int t  = threadIdx.x;
    const int lane = t & 63;
    const int wave = t >> 6;
    const int wm = (wave & 1) * 64;
    const int wn = (wave >> 1) * 64;
    const int lm = lane & 15;
    const int lq = lane >> 4;

    f32x4 acc[4][4] = {};

    // Staging: per K-iter each 8KB tile = 8 chunks of 1KB (16 rows x 64B).
    // Wave w stages chunks {2w, 2w+1}. Lane i -> row i>>2, col (i&3)*16B;
    // LDS byte offset 16*i (lane-contiguous).
    const int srow0 = wave * 32 + (lane >> 2);
    const int scol  = (lane & 3) * 8;
    const __bf16* ag0 = xb + (size_t)(bm + srow0) * D_IN + scol;
    const __bf16* ag1 = ag0 + 16 * D_IN;
    const __bf16* bg0 = wb + (size_t)(bn + srow0) * D_IN + scol;
    const __bf16* bg1 = bg0 + 16 * D_IN;
    __bf16* al0 = As + wave * 1024;
    __bf16* al1 = As + wave * 1024 + 512;
    __bf16* bl0 = Bs + wave * 1024;
    __bf16* bl1 = Bs + wave * 1024 + 512;

    for (int kk = 0; kk < D_IN; kk += BK) {
        gl_lds16(ag0 + kk, al0);
        gl_lds16(ag1 + kk, al1);
        gl_lds16(bg0 + kk, bl0);
        gl_lds16(bg1 + kk, bl1);
        __syncthreads();

        bf16x8 af[4], bfr[4];
#pragma unroll
        for (int i = 0; i < 4; ++i)
            af[i] = *(const bf16x8*)(&As[(wm + i * 16 + lm) * BK + lq * 8]);
#pragma unroll
        for (int i = 0; i < 4; ++i)
            bfr[i] = *(const bf16x8*)(&Bs[(wn + i * 16 + lm) * BK + lq * 8]);

#pragma unroll
        for (int i = 0; i < 4; ++i)
#pragma unroll
            for (int j = 0; j < 4; ++j)
                acc[i][j] = __builtin_amdgcn_mfma_f32_16x16x32_bf16(af[i], bfr[j], acc[i][j], 0, 0, 0);
        __syncthreads();
    }

    // C/D map: col = lane&15 (n), row = (lane>>4)*4 + reg (m)
#pragma unroll
    for (int j = 0; j < 4; ++j) {
        const int n = bn + wn + j * 16 + lm;
        const float sc = scale[n];
#pragma unroll
        for (int i = 0; i < 4; ++i) {
            const int m = bm + wm + i * 16 + lq * 4;
#pragma unroll
            for (int r = 0; r < 4; ++r) {
                out[(size_t)(m + r) * D_OUT + n] = acc[i][j][r] * sc;
            }
        }
    }
}

extern "C" void kernel_launch(void* const* d_in, const int* in_sizes, int n_in,
                              void* d_out, int out_size, void* d_ws, size_t ws_size,
                              hipStream_t stream) {
    const float* x    = (const float*)d_in[0];   // [4,8192,1024] fp32
    const float* w    = (const float*)d_in[1];   // [1024,1024]
    const float* a_w  = (const float*)d_in[2];   // [16,1024]
    const float* b_w  = (const float*)d_in[3];   // [1024,16]
    const float* mag  = (const float*)d_in[4];   // [1,1024]
    float* out = (float*)d_out;                  // [4,8192,1024] fp32

    __bf16* xb   = (__bf16*)d_ws;                                      // 64 MB
    __bf16* wb   = (__bf16*)((char*)d_ws + (size_t)M_TOT * D_IN * 2);  // 2 MB
    float* scale = (float*)((char*)wb + (size_t)D_OUT * D_IN * 2);     // 4 KB

    x_to_bf16<<<(M_TOT * D_IN) / (256 * 8), 256, 0, stream>>>(x, xb);
    dora_prep<<<D_OUT, 256, 0, stream>>>(w, a_w, b_w, mag, wb, scale);

    const int grid = (M_TOT / BM) * (D_OUT / BN);  // 2048
    dora_gemm<<<grid, 256, 0, stream>>>(xb, wb, scale, out);
}